// Round 1
// baseline (513.072 us; speedup 1.0000x reference)
//
#include <hip/hip_runtime.h>

// Problem constants (match reference setup_inputs)
#define N_TOTAL   524288   // TOTAL_FEATS
#define FACTORS   64
#define NFEAT     1024

__global__ void zero_out_kernel(float* out) {
    out[0] = 0.0f;
}

__global__ __launch_bounds__(256) void kgflex_gather_kernel(
    const int*   __restrict__ user,        // [B]
    const int*   __restrict__ sample_idx,  // [N_TOTAL]
    const int*   __restrict__ feat_idx,    // [N_TOTAL]
    const float* __restrict__ H,           // [NUM_USERS, FACTORS]
    const float* __restrict__ G,           // [NUM_FEATURES, FACTORS]
    const float* __restrict__ K,           // [NUM_USERS, NUM_FEATURES]
    float*       __restrict__ out)
{
    const int tid    = blockIdx.x * blockDim.x + threadIdx.x;
    const int stride = gridDim.x * blockDim.x;

    float local = 0.0f;

    for (int i = tid; i < N_TOTAL; i += stride) {
        const int b = sample_idx[i];
        const int f = feat_idx[i];
        const int u = user[b];

        const float4* hp = (const float4*)(H + (long)u * FACTORS);
        const float4* gp = (const float4*)(G + (long)f * FACTORS);

        float acc = 0.0f;
        #pragma unroll
        for (int k = 0; k < FACTORS / 4; ++k) {
            const float4 h = hp[k];
            const float4 g = gp[k];
            acc += h.x * g.x + h.y * g.y + h.z * g.z + h.w * g.w;
        }

        local += K[(long)u * NFEAT + f] * acc;
    }

    // wave-level reduction (wave = 64 lanes on gfx950)
    #pragma unroll
    for (int off = 32; off > 0; off >>= 1)
        local += __shfl_down(local, off, 64);

    __shared__ float smem[4];  // 256 threads = 4 waves
    const int lane = threadIdx.x & 63;
    const int wave = threadIdx.x >> 6;
    if (lane == 0) smem[wave] = local;
    __syncthreads();

    if (threadIdx.x == 0) {
        const float s = smem[0] + smem[1] + smem[2] + smem[3];
        atomicAdd(out, s);   // device-scope by default (G12)
    }
}

extern "C" void kernel_launch(void* const* d_in, const int* in_sizes, int n_in,
                              void* d_out, int out_size, void* d_ws, size_t ws_size,
                              hipStream_t stream) {
    const int*   user       = (const int*)d_in[0];
    const int*   sample_idx = (const int*)d_in[1];
    const int*   feat_idx   = (const int*)d_in[2];
    const float* H          = (const float*)d_in[3];
    const float* G          = (const float*)d_in[4];
    const float* K          = (const float*)d_in[5];
    float* out = (float*)d_out;

    // Harness poisons d_out with 0xAA before every launch — zero it first.
    zero_out_kernel<<<1, 1, 0, stream>>>(out);

    // 512 blocks x 256 threads -> each thread handles 4 entries (grid-stride)
    kgflex_gather_kernel<<<512, 256, 0, stream>>>(
        user, sample_idx, feat_idx, H, G, K, out);
}